// Round 9
// baseline (281.354 us; speedup 1.0000x reference)
//
#include <hip/hip_runtime.h>
#include <cstddef>
#include <cstdint>

// Problem constants (fixed by setup_inputs)
constexpr int B_SEG   = 4;
constexpr int N_C     = 4096;    // coarse points per batch
constexpr int M_F     = 16384;   // fine points per batch
constexpr int CIN     = 384;
constexpr int COUT    = 192;
constexpr int MT      = B_SEG * N_C;   // 16384 coarse rows
constexpr int MF      = B_SEG * M_F;   // 65536 fine rows
constexpr float LN_EPS = 1e-5f;

constexpr int GRES    = 16;            // KNN grid resolution (16^3 cells/batch)
constexpr int NCELL   = GRES * GRES * GRES;   // 4096

typedef __bf16 bf16x8 __attribute__((ext_vector_type(8)));
typedef __bf16 bf16x4 __attribute__((ext_vector_type(4)));
typedef float  f32x4  __attribute__((ext_vector_type(4)));

// ---------------------------------------------------------------------------
// K0: one-time prep — transpose+convert weights to bf16 [n][k] layout so the
// GEMM kernels load B-fragments as contiguous 16B global reads.
// ---------------------------------------------------------------------------
__global__ __launch_bounds__(256) void k0_prep(
    const float* __restrict__ w2, const float* __restrict__ w1,
    __bf16* __restrict__ wt2, __bf16* __restrict__ wt1)
{
  int e = blockIdx.x * 256 + threadIdx.x;
  if (e < CIN * COUT) {                       // w2: [384][192] -> wt2 [192][384]
    int k = e / COUT, n = e % COUT;
    wt2[(size_t)n * CIN + k] = (__bf16)w2[e];
  }
  e -= CIN * COUT;
  if (e >= 0 && e < COUT * COUT) {            // w1: [192][192] -> wt1 [192][192]
    int k = e / COUT, n = e % COUT;
    wt1[(size_t)n * COUT + k] = (__bf16)w1[e];
  }
}

// ---------------------------------------------------------------------------
// K1: h = LN(feats) @ w2 + b2      [16384 x 384] x [384 x 192]
// ---------------------------------------------------------------------------
__global__ __launch_bounds__(256) void k1_ln_gemm(
    const float* __restrict__ feats, const float* __restrict__ ln_g,
    const float* __restrict__ ln_b, const __bf16* __restrict__ wt2,
    const float* __restrict__ b2, float* __restrict__ h)
{
  __shared__ __align__(16) __bf16 As[64][CIN + 8];
  const int tid = threadIdx.x;
  const int blk = blockIdx.x;

  // ---- Phase 1: LN (4 threads/row, 24 float4 each) ----
  {
    const int r = tid >> 2, q = tid & 3;
    const float* frow = feats + (size_t)(blk * 64 + r) * CIN;
    float4 v[24];
    float sum = 0.f, sumsq = 0.f;
#pragma unroll
    for (int i = 0; i < 24; ++i) {
      float4 t = *(const float4*)(frow + (q + 4 * i) * 4);
      v[i] = t;
      sum   += (t.x + t.y) + (t.z + t.w);
      sumsq += (t.x * t.x + t.y * t.y) + (t.z * t.z + t.w * t.w);
    }
    sum   += __shfl_xor(sum, 1);  sumsq += __shfl_xor(sumsq, 1);
    sum   += __shfl_xor(sum, 2);  sumsq += __shfl_xor(sumsq, 2);
    float mean = sum * (1.f / CIN);
    float var  = sumsq * (1.f / CIN) - mean * mean;
    if (var < 0.f) var = 0.f;
    float rs = rsqrtf(var + LN_EPS);
#pragma unroll
    for (int i = 0; i < 24; ++i) {
      float4 g4 = *(const float4*)(ln_g + (q + 4 * i) * 4);
      float4 b4 = *(const float4*)(ln_b + (q + 4 * i) * 4);
      bf16x4 o;
      o[0] = (__bf16)((v[i].x - mean) * rs * g4.x + b4.x);
      o[1] = (__bf16)((v[i].y - mean) * rs * g4.y + b4.y);
      o[2] = (__bf16)((v[i].z - mean) * rs * g4.z + b4.z);
      o[3] = (__bf16)((v[i].w - mean) * rs * g4.w + b4.w);
      *(bf16x4*)&As[r][(q + 4 * i) * 4] = o;
    }
  }
  __syncthreads();

  // ---- Phase 2: MFMA ----
  const int w = tid >> 6, lane = tid & 63, m = lane & 15, half = lane >> 4;
  f32x4 acc[12];
#pragma unroll
  for (int t = 0; t < 12; ++t) acc[t] = (f32x4){0.f, 0.f, 0.f, 0.f};

  const __bf16* Arow = &As[16 * w + m][half * 8];
  const __bf16* Bbase = wt2 + (size_t)m * CIN + half * 8;
#pragma unroll
  for (int ch = 0; ch < 12; ++ch) {
    bf16x8 a = *(const bf16x8*)(Arow + ch * 32);
#pragma unroll
    for (int t = 0; t < 12; ++t) {
      bf16x8 b = *(const bf16x8*)(Bbase + (size_t)(16 * t) * CIN + ch * 32);
      acc[t] = __builtin_amdgcn_mfma_f32_16x16x32_bf16(a, b, acc[t], 0, 0, 0);
    }
  }

  // ---- Epilogue: D layout col=lane&15, row=(lane>>4)*4+reg ----
  const int r0 = blk * 64 + 16 * w + half * 4;
#pragma unroll
  for (int t = 0; t < 12; ++t) {
    float bv = b2[16 * t + m];
#pragma unroll
    for (int reg = 0; reg < 4; ++reg)
      h[(size_t)(r0 + reg) * COUT + 16 * t + m] = acc[t][reg] + bv;
  }
}

// ---------------------------------------------------------------------------
// KNN helpers: exact-rounding distance; u64 key (d2_bits<<32)|idx compared
// lexicographically == jax.lax.top_k stable order; order-independent.
// ---------------------------------------------------------------------------
__device__ __forceinline__ float dist2_rn(float px, float py, float pz,
                                          float sx, float sy, float sz)
{
  float dx = __fsub_rn(px, sx);
  float dy = __fsub_rn(py, sy);
  float dz = __fsub_rn(pz, sz);
  return __fadd_rn(__fadd_rn(__fmul_rn(dx, dx), __fmul_rn(dy, dy)),
                   __fmul_rn(dz, dz));
}

// merge two sorted triples -> 3 smallest of the union (branchless 2-pointer).
// PRECONDITION: the two triples come from DISJOINT candidate sets (no shared
// keys) — otherwise shared keys are double-counted.
__device__ __forceinline__ void merge3(
    unsigned long long& a0, unsigned long long& a1, unsigned long long& a2,
    unsigned long long b0, unsigned long long b1, unsigned long long b2)
{
  bool t = a0 <= b0;
  unsigned long long r0 = t ? a0 : b0;
  unsigned long long A0 = t ? a1 : a0;
  unsigned long long A1 = t ? a2 : a1;
  unsigned long long B0 = t ? b0 : b1;
  unsigned long long B1 = t ? b1 : b2;
  t = A0 <= B0;
  unsigned long long r1 = t ? A0 : B0;
  unsigned long long C0 = t ? A1 : A0;
  unsigned long long D0 = t ? B0 : B1;
  unsigned long long r2 = C0 <= D0 ? C0 : D0;
  a0 = r0; a1 = r1; a2 = r2;
}

// Quad-wide merged view of 4 PRIVATE per-lane triples -> temporaries m0..m2.
// R6 BUG FIX: never write merged values back into the private lists. The
// private lists are disjoint across the quad by construction, so:
//   step 1: m = top3(list_l  U  list_{l^1})        (disjoint pair)
//   step 2: m = top3(pairU_l U  pairU_{l^2})       (disjoint pair-unions)
// All 4 lanes end with the identical exact global top-3.
__device__ __forceinline__ void quad_merge(
    unsigned long long bk0, unsigned long long bk1, unsigned long long bk2,
    unsigned long long& m0, unsigned long long& m1, unsigned long long& m2)
{
  m0 = bk0; m1 = bk1; m2 = bk2;
  merge3(m0, m1, m2, __shfl_xor(bk0, 1), __shfl_xor(bk1, 1), __shfl_xor(bk2, 1));
  merge3(m0, m1, m2, __shfl_xor(m0, 2), __shfl_xor(m1, 2), __shfl_xor(m2, 2));
}

// ---------------------------------------------------------------------------
// KG: grid build — one block per batch. LDS histogram over 16^3 cells,
// exclusive scan, then counting-sort scatter of float4(x,y,z,id_bits) into a
// cell-sorted AoS array in workspace. 4096 points per block.
// ---------------------------------------------------------------------------
__global__ __launch_bounds__(256) void kgrid(
    const float* __restrict__ xyz,
    float4* __restrict__ pts_g, uint32_t* __restrict__ starts_g)
{
  __shared__ uint32_t cnt[NCELL];
  __shared__ uint32_t bsum[256];
  const int t = threadIdx.x;
  const int b = blockIdx.x;
  const float* src = xyz + (size_t)b * N_C * 3;

#pragma unroll
  for (int i = 0; i < NCELL / 256; ++i) cnt[t + 256 * i] = 0u;
  __syncthreads();

  int   cl[16];
  float xr[16], yr[16], zr[16];
#pragma unroll
  for (int i = 0; i < 16; ++i) {
    int p = i * 256 + t;
    float x = src[3 * p + 0], y = src[3 * p + 1], z = src[3 * p + 2];
    xr[i] = x; yr[i] = y; zr[i] = z;
    int ix = min(GRES - 1, max(0, (int)(x * (float)GRES)));
    int iy = min(GRES - 1, max(0, (int)(y * (float)GRES)));
    int iz = min(GRES - 1, max(0, (int)(z * (float)GRES)));
    int c = (ix << 8) | (iy << 4) | iz;
    cl[i] = c;
    atomicAdd(&cnt[c], 1u);
  }
  __syncthreads();

  // exclusive scan of cnt[4096]: per-thread 16-seq + Hillis-Steele over 256
  uint32_t loc[16], s = 0;
#pragma unroll
  for (int j = 0; j < 16; ++j) { loc[j] = cnt[t * 16 + j]; s += loc[j]; }
  bsum[t] = s;
  __syncthreads();
  for (int off = 1; off < 256; off <<= 1) {
    uint32_t v = (t >= off) ? bsum[t - off] : 0u;
    __syncthreads();
    bsum[t] += v;
    __syncthreads();
  }
  uint32_t run = bsum[t] - s;          // exclusive block offset
#pragma unroll
  for (int j = 0; j < 16; ++j) { cnt[t * 16 + j] = run; run += loc[j]; }
  __syncthreads();

  // dump starts to global (before cnt is mutated by the scatter cursors)
#pragma unroll
  for (int i = 0; i < NCELL / 256; ++i)
    starts_g[(size_t)b * (NCELL + 1) + t + 256 * i] = cnt[t + 256 * i];
  if (t == 0) starts_g[(size_t)b * (NCELL + 1) + NCELL] = N_C;
  __syncthreads();

  // counting-sort scatter (within-cell order nondeterministic — OK, the
  // search comparator is order-independent)
#pragma unroll
  for (int i = 0; i < 16; ++i) {
    int p = i * 256 + t;
    uint32_t pos = atomicAdd(&cnt[cl[i]], 1u);
    size_t o = (size_t)b * N_C + pos;
    pts_g[o] = make_float4(xr[i], yr[i], zr[i], __uint_as_float((uint32_t)p));
  }
}

// ---------------------------------------------------------------------------
// KNN search v3: quad-parallel (4 lanes/query), duplicate-safe merging.
// Private per-lane top-3 over a sub-strided (disjoint) candidate partition;
// merged views computed into temporaries only (quad_merge) for the ring stop
// rule and the final output. Stop rule: t2 < (R*h)^2*(1-1e-6), quad-uniform.
// ---------------------------------------------------------------------------
__global__ __launch_bounds__(256) void kknn(
    const float* __restrict__ sxyz,
    const float4* __restrict__ pts_g, const uint32_t* __restrict__ starts_g,
    int* __restrict__ knn_i, float* __restrict__ knn_w)
{
  __shared__ uint32_t starts[NCELL + 1];
  const int tid = threadIdx.x;
  const int blk = blockIdx.x;            // 1024 blocks, 256 per batch
  const int b   = blk >> 8;

#pragma unroll
  for (int i = 0; i < 17; ++i) {
    int k = tid + 256 * i;
    if (k < NCELL + 1) starts[k] = starts_g[(size_t)b * (NCELL + 1) + k];
  }

  const float4* pb = pts_g + (size_t)b * N_C;
  const int sub = tid & 3;
  const int dst = blk * 64 + (tid >> 2);
  const float px = sxyz[(size_t)dst * 3 + 0];
  const float py = sxyz[(size_t)dst * 3 + 1];
  const float pz = sxyz[(size_t)dst * 3 + 2];
  const int cx = min(GRES - 1, max(0, (int)(px * (float)GRES)));
  const int cy = min(GRES - 1, max(0, (int)(py * (float)GRES)));
  const int cz = min(GRES - 1, max(0, (int)(pz * (float)GRES)));
  __syncthreads();

  unsigned long long bk0 = ~0ull, bk1 = ~0ull, bk2 = ~0ull;   // PRIVATE

  // shells 0..1: 3x3x3 box around the query cell, strided by sub
  for (int xx = cx - 1; xx <= cx + 1; ++xx) {
    if ((unsigned)xx > (unsigned)(GRES - 1)) continue;
    for (int yy = cy - 1; yy <= cy + 1; ++yy) {
      if ((unsigned)yy > (unsigned)(GRES - 1)) continue;
      for (int zz = cz - 1; zz <= cz + 1; ++zz) {
        if ((unsigned)zz > (unsigned)(GRES - 1)) continue;
        int c = (xx << 8) | (yy << 4) | zz;
        for (uint32_t i = starts[c] + sub, e = starts[c + 1]; i < e; i += 4) {
          float4 p4 = pb[i];
          float d2 = dist2_rn(px, py, pz, p4.x, p4.y, p4.z);
          unsigned long long key =
              ((unsigned long long)__float_as_uint(d2) << 32) |
              (unsigned long long)__float_as_uint(p4.w);
          bool i0 = key < bk0, i1 = key < bk1, i2 = key < bk2;
          bk2 = i1 ? bk1 : (i2 ? key : bk2);
          bk1 = i0 ? bk0 : (i1 ? key : bk1);
          bk0 = i0 ? key : bk0;
        }
      }
    }
  }

  unsigned long long m0, m1, m2;
  quad_merge(bk0, bk1, bk2, m0, m1, m2);

  const float H = 1.0f / (float)GRES;
  float t2f = __uint_as_float((uint32_t)(m2 >> 32));    // NaN while <3 found
  if (!(t2f < H * H * 0.999999f)) {
    for (int R = 2; R <= GRES - 1; ++R) {
      int x0 = max(cx - R, 0), x1 = min(cx + R, GRES - 1);
      int y0 = max(cy - R, 0), y1 = min(cy + R, GRES - 1);
      int z0 = max(cz - R, 0), z1 = min(cz + R, GRES - 1);
      for (int xx = x0; xx <= x1; ++xx) {
        int ax = abs(xx - cx);
        for (int yy = y0; yy <= y1; ++yy) {
          int ay = abs(yy - cy);
          for (int zz = z0; zz <= z1; ++zz) {
            int ch = max(ax, max(ay, abs(zz - cz)));
            if (ch != R) continue;                     // shell only
            int c = (xx << 8) | (yy << 4) | zz;
            for (uint32_t i = starts[c] + sub, e = starts[c + 1]; i < e; i += 4) {
              float4 p4 = pb[i];
              float d2 = dist2_rn(px, py, pz, p4.x, p4.y, p4.z);
              unsigned long long key =
                  ((unsigned long long)__float_as_uint(d2) << 32) |
                  (unsigned long long)__float_as_uint(p4.w);
              bool i0 = key < bk0, i1 = key < bk1, i2 = key < bk2;
              bk2 = i1 ? bk1 : (i2 ? key : bk2);
              bk1 = i0 ? bk0 : (i1 ? key : bk1);
              bk0 = i0 ? key : bk0;
            }
          }
        }
      }
      quad_merge(bk0, bk1, bk2, m0, m1, m2);
      t2f = __uint_as_float((uint32_t)(m2 >> 32));
      float thr = (float)R * H;
      if (t2f < thr * thr * 0.999999f) break;
    }
  }

  if (sub == 0) {
    float d0  = sqrtf(__uint_as_float((uint32_t)(m0 >> 32)));
    float d1  = sqrtf(__uint_as_float((uint32_t)(m1 >> 32)));
    float d2s = sqrtf(__uint_as_float((uint32_t)(m2 >> 32)));
    float r0 = 1.f / (d0 + 1e-8f);
    float r1 = 1.f / (d1 + 1e-8f);
    float r2 = 1.f / (d2s + 1e-8f);
    float inv = 1.f / (r0 + r1 + r2);
    const int jb = b * N_C;
    knn_i[(size_t)dst * 3 + 0] = jb + (int)(m0 & 0xffffffffull);
    knn_i[(size_t)dst * 3 + 1] = jb + (int)(m1 & 0xffffffffull);
    knn_i[(size_t)dst * 3 + 2] = jb + (int)(m2 & 0xffffffffull);
    knn_w[(size_t)dst * 3 + 0] = r0 * inv;
    knn_w[(size_t)dst * 3 + 1] = r1 * inv;
    knn_w[(size_t)dst * 3 + 2] = r2 * inv;
  }
}

// ---------------------------------------------------------------------------
// K3: out = LN(support_feats) @ w1 + b1 + interp(h)   [65536 x 192] x [192 x 192]
// GEMM result staged in BF16 (reusing the 25.6 KB A-tile buffer) instead of a
// second 50 KB f32 buffer. LDS 50 KB -> 25.6 KB lets all 4 blocks/CU be
// resident in one round (was 3+1 serial rounds at 19.7% occupancy).
// Staging precision cost ~0.004*|c| — negligible vs the 0.1 bf16-GEMM floor.
// ---------------------------------------------------------------------------
__global__ __launch_bounds__(256) void k3_ln_gemm_interp(
    const float* __restrict__ sfeats, const float* __restrict__ ln_g,
    const float* __restrict__ ln_b, const __bf16* __restrict__ wt1,
    const float* __restrict__ b1, const float* __restrict__ h,
    const int* __restrict__ knn_i, const float* __restrict__ knn_w,
    float* __restrict__ out)
{
  // single 25.6 KB buffer: A-tile (phases 1-2), then bf16 C-stage (epilogue)
  __shared__ __align__(16) __bf16 sm[64][COUT + 8];
  const int tid = threadIdx.x;
  const int blk = blockIdx.x;

  // ---- Phase 1: LN (4 threads/row, 12 float4 each) ----
  {
    const int r = tid >> 2, q = tid & 3;
    const float* frow = sfeats + (size_t)(blk * 64 + r) * COUT;
    float4 v[12];
    float sum = 0.f, sumsq = 0.f;
#pragma unroll
    for (int i = 0; i < 12; ++i) {
      float4 t = *(const float4*)(frow + (q + 4 * i) * 4);
      v[i] = t;
      sum   += (t.x + t.y) + (t.z + t.w);
      sumsq += (t.x * t.x + t.y * t.y) + (t.z * t.z + t.w * t.w);
    }
    sum   += __shfl_xor(sum, 1);  sumsq += __shfl_xor(sumsq, 1);
    sum   += __shfl_xor(sum, 2);  sumsq += __shfl_xor(sumsq, 2);
    float mean = sum * (1.f / COUT);
    float var  = sumsq * (1.f / COUT) - mean * mean;
    if (var < 0.f) var = 0.f;
    float rs = rsqrtf(var + LN_EPS);
#pragma unroll
    for (int i = 0; i < 12; ++i) {
      float4 g4 = *(const float4*)(ln_g + (q + 4 * i) * 4);
      float4 b4 = *(const float4*)(ln_b + (q + 4 * i) * 4);
      bf16x4 o;
      o[0] = (__bf16)((v[i].x - mean) * rs * g4.x + b4.x);
      o[1] = (__bf16)((v[i].y - mean) * rs * g4.y + b4.y);
      o[2] = (__bf16)((v[i].z - mean) * rs * g4.z + b4.z);
      o[3] = (__bf16)((v[i].w - mean) * rs * g4.w + b4.w);
      *(bf16x4*)&sm[r][(q + 4 * i) * 4] = o;
    }
  }
  __syncthreads();

  // ---- Phase 2: MFMA ----
  const int w = tid >> 6, lane = tid & 63, m = lane & 15, half = lane >> 4;
  f32x4 acc[12];
#pragma unroll
  for (int t = 0; t < 12; ++t) acc[t] = (f32x4){0.f, 0.f, 0.f, 0.f};

  const __bf16* Arow = &sm[16 * w + m][half * 8];
  const __bf16* Bbase = wt1 + (size_t)m * COUT + half * 8;
#pragma unroll
  for (int ch = 0; ch < 6; ++ch) {
    bf16x8 a = *(const bf16x8*)(Arow + ch * 32);
#pragma unroll
    for (int t = 0; t < 12; ++t) {
      bf16x8 b = *(const bf16x8*)(Bbase + (size_t)(16 * t) * COUT + ch * 32);
      acc[t] = __builtin_amdgcn_mfma_f32_16x16x32_bf16(a, b, acc[t], 0, 0, 0);
    }
  }

  // ---- Stage acc+bias into LDS as bf16 (A-tile no longer needed) ----
  float bv[12];
#pragma unroll
  for (int t = 0; t < 12; ++t) bv[t] = b1[16 * t + m];
  __syncthreads();
  {
    const int rr = 16 * w + half * 4;
#pragma unroll
    for (int t = 0; t < 12; ++t)
#pragma unroll
      for (int reg = 0; reg < 4; ++reg)
        sm[rr + reg][16 * t + m] = (__bf16)(acc[t][reg] + bv[t]);
  }
  __syncthreads();

  // ---- Vectorized interp + store: 4 threads per row, float4 gathers ----
  {
    const int r = tid >> 2, q = tid & 3;
    const int R = blk * 64 + r;
    int   i0 = knn_i[(size_t)R * 3 + 0];
    int   i1 = knn_i[(size_t)R * 3 + 1];
    int   i2 = knn_i[(size_t)R * 3 + 2];
    float w0 = knn_w[(size_t)R * 3 + 0];
    float w1v = knn_w[(size_t)R * 3 + 1];
    float w2v = knn_w[(size_t)R * 3 + 2];
    const float* h0 = h + (size_t)i0 * COUT;
    const float* h1 = h + (size_t)i1 * COUT;
    const float* h2 = h + (size_t)i2 * COUT;
    float* orow = out + (size_t)R * COUT;
#pragma unroll
    for (int i = 0; i < 12; ++i) {
      const int col = 16 * i + 4 * q;
      bf16x4 c4 = *(const bf16x4*)&sm[r][col];
      f32x4 g0 = *(const f32x4*)(h0 + col);
      f32x4 g1 = *(const f32x4*)(h1 + col);
      f32x4 g2 = *(const f32x4*)(h2 + col);
      f32x4 o;
      o[0] = (float)c4[0] + w0 * g0[0] + w1v * g1[0] + w2v * g2[0];
      o[1] = (float)c4[1] + w0 * g0[1] + w1v * g1[1] + w2v * g2[1];
      o[2] = (float)c4[2] + w0 * g0[2] + w1v * g1[2] + w2v * g2[2];
      o[3] = (float)c4[3] + w0 * g0[3] + w1v * g1[3] + w2v * g2[3];
      *(f32x4*)(orow + col) = o;
    }
  }
}

// ---------------------------------------------------------------------------
// K4: passthrough outputs — support_xyz copy + support_offset as float
// ---------------------------------------------------------------------------
__global__ __launch_bounds__(256) void k4_tail(
    const float* __restrict__ sxyz, const int* __restrict__ soff,
    float* __restrict__ out_tail)
{
  const int t = blockIdx.x * 256 + threadIdx.x;
  if (t < MF * 3) out_tail[t] = sxyz[t];
  if (t < B_SEG) out_tail[MF * 3 + t] = (float)soff[t];
}

// ---------------------------------------------------------------------------
extern "C" void kernel_launch(void* const* d_in, const int* in_sizes, int n_in,
                              void* d_out, int out_size, void* d_ws, size_t ws_size,
                              hipStream_t stream)
{
  const float* feats  = (const float*)d_in[0];
  const float* xyz    = (const float*)d_in[1];
  const float* sxyz   = (const float*)d_in[2];
  const float* sfeats = (const float*)d_in[3];
  const int*   soff   = (const int*)d_in[5];
  const float* ln1_g  = (const float*)d_in[6];
  const float* ln1_b  = (const float*)d_in[7];
  const float* w1     = (const float*)d_in[8];
  const float* b1     = (const float*)d_in[9];
  const float* ln2_g  = (const float*)d_in[10];
  const float* ln2_b  = (const float*)d_in[11];
  const float* w2     = (const float*)d_in[12];
  const float* b2     = (const float*)d_in[13];
  float* out = (float*)d_out;

  // workspace layout (float units)
  float*    h       = (float*)d_ws;                        // 16384*192 f32
  int*      knn_i   = (int*)(h + (size_t)MT * COUT);       // 65536*3
  float*    knn_w   = (float*)(knn_i + (size_t)MF * 3);    // 65536*3
  float4*   pts_g   = (float4*)(knn_w + (size_t)MF * 3);   // 4*4096 float4
  uint32_t* starts_g= (uint32_t*)(pts_g + (size_t)B_SEG * N_C);   // 4*4097
  __bf16*   wt2     = (__bf16*)(starts_g + (size_t)B_SEG * (NCELL + 1));
  __bf16*   wt1     = wt2 + (size_t)COUT * CIN;

  k0_prep<<<(CIN * COUT + COUT * COUT) / 256, 256, 0, stream>>>(w2, w1, wt2, wt1);
  kgrid<<<B_SEG, 256, 0, stream>>>(xyz, pts_g, starts_g);
  k1_ln_gemm<<<MT / 64, 256, 0, stream>>>(feats, ln2_g, ln2_b, wt2, b2, h);
  kknn<<<(MF * 4) / 256, 256, 0, stream>>>(sxyz, pts_g, starts_g, knn_i, knn_w);
  k3_ln_gemm_interp<<<MF / 64, 256, 0, stream>>>(sfeats, ln1_g, ln1_b, wt1, b1,
                                                 h, knn_i, knn_w, out);
  k4_tail<<<(MF * 3) / 256, 256, 0, stream>>>(sxyz, soff, out + (size_t)MF * COUT);
}

// Round 10
// 278.016 us; speedup vs baseline: 1.0120x; 1.0120x over previous
//
#include <hip/hip_runtime.h>
#include <cstddef>
#include <cstdint>

// Problem constants (fixed by setup_inputs)
constexpr int B_SEG   = 4;
constexpr int N_C     = 4096;    // coarse points per batch
constexpr int M_F     = 16384;   // fine points per batch
constexpr int CIN     = 384;
constexpr int COUT    = 192;
constexpr int MT      = B_SEG * N_C;   // 16384 coarse rows
constexpr int MF      = B_SEG * M_F;   // 65536 fine rows
constexpr float LN_EPS = 1e-5f;

constexpr int GRES    = 16;            // KNN grid resolution (16^3 cells/batch)
constexpr int NCELL   = GRES * GRES * GRES;   // 4096

typedef __bf16 bf16x8 __attribute__((ext_vector_type(8)));
typedef __bf16 bf16x4 __attribute__((ext_vector_type(4)));
typedef float  f32x4  __attribute__((ext_vector_type(4)));

// ---------------------------------------------------------------------------
// K0: one-time prep — transpose+convert weights to bf16 [n][k] layout so the
// GEMM kernels load B-fragments as contiguous 16B global reads.
// ---------------------------------------------------------------------------
__global__ __launch_bounds__(256) void k0_prep(
    const float* __restrict__ w2, const float* __restrict__ w1,
    __bf16* __restrict__ wt2, __bf16* __restrict__ wt1)
{
  int e = blockIdx.x * 256 + threadIdx.x;
  if (e < CIN * COUT) {                       // w2: [384][192] -> wt2 [192][384]
    int k = e / COUT, n = e % COUT;
    wt2[(size_t)n * CIN + k] = (__bf16)w2[e];
  }
  e -= CIN * COUT;
  if (e >= 0 && e < COUT * COUT) {            // w1: [192][192] -> wt1 [192][192]
    int k = e / COUT, n = e % COUT;
    wt1[(size_t)n * COUT + k] = (__bf16)w1[e];
  }
}

// ---------------------------------------------------------------------------
// K1: h = LN(feats) @ w2 + b2      [16384 x 384] x [384 x 192]
// ---------------------------------------------------------------------------
__global__ __launch_bounds__(256) void k1_ln_gemm(
    const float* __restrict__ feats, const float* __restrict__ ln_g,
    const float* __restrict__ ln_b, const __bf16* __restrict__ wt2,
    const float* __restrict__ b2, float* __restrict__ h)
{
  __shared__ __align__(16) __bf16 As[64][CIN + 8];
  const int tid = threadIdx.x;
  const int blk = blockIdx.x;

  // ---- Phase 1: LN (4 threads/row, 24 float4 each) ----
  {
    const int r = tid >> 2, q = tid & 3;
    const float* frow = feats + (size_t)(blk * 64 + r) * CIN;
    float4 v[24];
    float sum = 0.f, sumsq = 0.f;
#pragma unroll
    for (int i = 0; i < 24; ++i) {
      float4 t = *(const float4*)(frow + (q + 4 * i) * 4);
      v[i] = t;
      sum   += (t.x + t.y) + (t.z + t.w);
      sumsq += (t.x * t.x + t.y * t.y) + (t.z * t.z + t.w * t.w);
    }
    sum   += __shfl_xor(sum, 1);  sumsq += __shfl_xor(sumsq, 1);
    sum   += __shfl_xor(sum, 2);  sumsq += __shfl_xor(sumsq, 2);
    float mean = sum * (1.f / CIN);
    float var  = sumsq * (1.f / CIN) - mean * mean;
    if (var < 0.f) var = 0.f;
    float rs = rsqrtf(var + LN_EPS);
#pragma unroll
    for (int i = 0; i < 24; ++i) {
      float4 g4 = *(const float4*)(ln_g + (q + 4 * i) * 4);
      float4 b4 = *(const float4*)(ln_b + (q + 4 * i) * 4);
      bf16x4 o;
      o[0] = (__bf16)((v[i].x - mean) * rs * g4.x + b4.x);
      o[1] = (__bf16)((v[i].y - mean) * rs * g4.y + b4.y);
      o[2] = (__bf16)((v[i].z - mean) * rs * g4.z + b4.z);
      o[3] = (__bf16)((v[i].w - mean) * rs * g4.w + b4.w);
      *(bf16x4*)&As[r][(q + 4 * i) * 4] = o;
    }
  }
  __syncthreads();

  // ---- Phase 2: MFMA ----
  const int w = tid >> 6, lane = tid & 63, m = lane & 15, half = lane >> 4;
  f32x4 acc[12];
#pragma unroll
  for (int t = 0; t < 12; ++t) acc[t] = (f32x4){0.f, 0.f, 0.f, 0.f};

  const __bf16* Arow = &As[16 * w + m][half * 8];
  const __bf16* Bbase = wt2 + (size_t)m * CIN + half * 8;
#pragma unroll
  for (int ch = 0; ch < 12; ++ch) {
    bf16x8 a = *(const bf16x8*)(Arow + ch * 32);
#pragma unroll
    for (int t = 0; t < 12; ++t) {
      bf16x8 b = *(const bf16x8*)(Bbase + (size_t)(16 * t) * CIN + ch * 32);
      acc[t] = __builtin_amdgcn_mfma_f32_16x16x32_bf16(a, b, acc[t], 0, 0, 0);
    }
  }

  // ---- Epilogue: D layout col=lane&15, row=(lane>>4)*4+reg ----
  const int r0 = blk * 64 + 16 * w + half * 4;
#pragma unroll
  for (int t = 0; t < 12; ++t) {
    float bv = b2[16 * t + m];
#pragma unroll
    for (int reg = 0; reg < 4; ++reg)
      h[(size_t)(r0 + reg) * COUT + 16 * t + m] = acc[t][reg] + bv;
  }
}

// ---------------------------------------------------------------------------
// KNN helpers: exact-rounding distance; u64 key (d2_bits<<32)|idx compared
// lexicographically == jax.lax.top_k stable order; order-independent.
// ---------------------------------------------------------------------------
__device__ __forceinline__ float dist2_rn(float px, float py, float pz,
                                          float sx, float sy, float sz)
{
  float dx = __fsub_rn(px, sx);
  float dy = __fsub_rn(py, sy);
  float dz = __fsub_rn(pz, sz);
  return __fadd_rn(__fadd_rn(__fmul_rn(dx, dx), __fmul_rn(dy, dy)),
                   __fmul_rn(dz, dz));
}

// merge two sorted triples -> 3 smallest of the union (branchless 2-pointer).
// PRECONDITION: the two triples come from DISJOINT candidate sets (no shared
// keys) — otherwise shared keys are double-counted.
__device__ __forceinline__ void merge3(
    unsigned long long& a0, unsigned long long& a1, unsigned long long& a2,
    unsigned long long b0, unsigned long long b1, unsigned long long b2)
{
  bool t = a0 <= b0;
  unsigned long long r0 = t ? a0 : b0;
  unsigned long long A0 = t ? a1 : a0;
  unsigned long long A1 = t ? a2 : a1;
  unsigned long long B0 = t ? b0 : b1;
  unsigned long long B1 = t ? b1 : b2;
  t = A0 <= B0;
  unsigned long long r1 = t ? A0 : B0;
  unsigned long long C0 = t ? A1 : A0;
  unsigned long long D0 = t ? B0 : B1;
  unsigned long long r2 = C0 <= D0 ? C0 : D0;
  a0 = r0; a1 = r1; a2 = r2;
}

// Quad-wide merged view of 4 PRIVATE per-lane triples -> temporaries m0..m2.
// Never write merged values back into the private lists (disjointness).
__device__ __forceinline__ void quad_merge(
    unsigned long long bk0, unsigned long long bk1, unsigned long long bk2,
    unsigned long long& m0, unsigned long long& m1, unsigned long long& m2)
{
  m0 = bk0; m1 = bk1; m2 = bk2;
  merge3(m0, m1, m2, __shfl_xor(bk0, 1), __shfl_xor(bk1, 1), __shfl_xor(bk2, 1));
  merge3(m0, m1, m2, __shfl_xor(m0, 2), __shfl_xor(m1, 2), __shfl_xor(m2, 2));
}

// ---------------------------------------------------------------------------
// KG: grid build — one block per batch. LDS histogram over 16^3 cells,
// exclusive scan, then counting-sort scatter of float4(x,y,z,id_bits) into a
// cell-sorted AoS array in workspace. 4096 points per block.
// ---------------------------------------------------------------------------
__global__ __launch_bounds__(256) void kgrid(
    const float* __restrict__ xyz,
    float4* __restrict__ pts_g, uint32_t* __restrict__ starts_g)
{
  __shared__ uint32_t cnt[NCELL];
  __shared__ uint32_t bsum[256];
  const int t = threadIdx.x;
  const int b = blockIdx.x;
  const float* src = xyz + (size_t)b * N_C * 3;

#pragma unroll
  for (int i = 0; i < NCELL / 256; ++i) cnt[t + 256 * i] = 0u;
  __syncthreads();

  int   cl[16];
  float xr[16], yr[16], zr[16];
#pragma unroll
  for (int i = 0; i < 16; ++i) {
    int p = i * 256 + t;
    float x = src[3 * p + 0], y = src[3 * p + 1], z = src[3 * p + 2];
    xr[i] = x; yr[i] = y; zr[i] = z;
    int ix = min(GRES - 1, max(0, (int)(x * (float)GRES)));
    int iy = min(GRES - 1, max(0, (int)(y * (float)GRES)));
    int iz = min(GRES - 1, max(0, (int)(z * (float)GRES)));
    int c = (ix << 8) | (iy << 4) | iz;
    cl[i] = c;
    atomicAdd(&cnt[c], 1u);
  }
  __syncthreads();

  // exclusive scan of cnt[4096]: per-thread 16-seq + Hillis-Steele over 256
  uint32_t loc[16], s = 0;
#pragma unroll
  for (int j = 0; j < 16; ++j) { loc[j] = cnt[t * 16 + j]; s += loc[j]; }
  bsum[t] = s;
  __syncthreads();
  for (int off = 1; off < 256; off <<= 1) {
    uint32_t v = (t >= off) ? bsum[t - off] : 0u;
    __syncthreads();
    bsum[t] += v;
    __syncthreads();
  }
  uint32_t run = bsum[t] - s;          // exclusive block offset
#pragma unroll
  for (int j = 0; j < 16; ++j) { cnt[t * 16 + j] = run; run += loc[j]; }
  __syncthreads();

  // dump starts to global (before cnt is mutated by the scatter cursors)
#pragma unroll
  for (int i = 0; i < NCELL / 256; ++i)
    starts_g[(size_t)b * (NCELL + 1) + t + 256 * i] = cnt[t + 256 * i];
  if (t == 0) starts_g[(size_t)b * (NCELL + 1) + NCELL] = N_C;
  __syncthreads();

  // counting-sort scatter (within-cell order nondeterministic — OK, the
  // search comparator is order-independent)
#pragma unroll
  for (int i = 0; i < 16; ++i) {
    int p = i * 256 + t;
    uint32_t pos = atomicAdd(&cnt[cl[i]], 1u);
    size_t o = (size_t)b * N_C + pos;
    pts_g[o] = make_float4(xr[i], yr[i], zr[i], __uint_as_float((uint32_t)p));
  }
}

// ---------------------------------------------------------------------------
// KNN search: quad-parallel (4 lanes/query), duplicate-safe merging (R9-
// verified). Private per-lane top-3 over a sub-strided partition; merged
// views in temporaries only; stop rule t2 < (R*h)^2*(1-1e-6), quad-uniform.
// ---------------------------------------------------------------------------
__global__ __launch_bounds__(256) void kknn(
    const float* __restrict__ sxyz,
    const float4* __restrict__ pts_g, const uint32_t* __restrict__ starts_g,
    int* __restrict__ knn_i, float* __restrict__ knn_w)
{
  __shared__ uint32_t starts[NCELL + 1];
  const int tid = threadIdx.x;
  const int blk = blockIdx.x;            // 1024 blocks, 256 per batch
  const int b   = blk >> 8;

#pragma unroll
  for (int i = 0; i < 17; ++i) {
    int k = tid + 256 * i;
    if (k < NCELL + 1) starts[k] = starts_g[(size_t)b * (NCELL + 1) + k];
  }

  const float4* pb = pts_g + (size_t)b * N_C;
  const int sub = tid & 3;
  const int dst = blk * 64 + (tid >> 2);
  const float px = sxyz[(size_t)dst * 3 + 0];
  const float py = sxyz[(size_t)dst * 3 + 1];
  const float pz = sxyz[(size_t)dst * 3 + 2];
  const int cx = min(GRES - 1, max(0, (int)(px * (float)GRES)));
  const int cy = min(GRES - 1, max(0, (int)(py * (float)GRES)));
  const int cz = min(GRES - 1, max(0, (int)(pz * (float)GRES)));
  __syncthreads();

  unsigned long long bk0 = ~0ull, bk1 = ~0ull, bk2 = ~0ull;   // PRIVATE

  // shells 0..1: 3x3x3 box around the query cell, strided by sub
  for (int xx = cx - 1; xx <= cx + 1; ++xx) {
    if ((unsigned)xx > (unsigned)(GRES - 1)) continue;
    for (int yy = cy - 1; yy <= cy + 1; ++yy) {
      if ((unsigned)yy > (unsigned)(GRES - 1)) continue;
      for (int zz = cz - 1; zz <= cz + 1; ++zz) {
        if ((unsigned)zz > (unsigned)(GRES - 1)) continue;
        int c = (xx << 8) | (yy << 4) | zz;
        for (uint32_t i = starts[c] + sub, e = starts[c + 1]; i < e; i += 4) {
          float4 p4 = pb[i];
          float d2 = dist2_rn(px, py, pz, p4.x, p4.y, p4.z);
          unsigned long long key =
              ((unsigned long long)__float_as_uint(d2) << 32) |
              (unsigned long long)__float_as_uint(p4.w);
          bool i0 = key < bk0, i1 = key < bk1, i2 = key < bk2;
          bk2 = i1 ? bk1 : (i2 ? key : bk2);
          bk1 = i0 ? bk0 : (i1 ? key : bk1);
          bk0 = i0 ? key : bk0;
        }
      }
    }
  }

  unsigned long long m0, m1, m2;
  quad_merge(bk0, bk1, bk2, m0, m1, m2);

  const float H = 1.0f / (float)GRES;
  float t2f = __uint_as_float((uint32_t)(m2 >> 32));    // NaN while <3 found
  if (!(t2f < H * H * 0.999999f)) {
    for (int R = 2; R <= GRES - 1; ++R) {
      int x0 = max(cx - R, 0), x1 = min(cx + R, GRES - 1);
      int y0 = max(cy - R, 0), y1 = min(cy + R, GRES - 1);
      int z0 = max(cz - R, 0), z1 = min(cz + R, GRES - 1);
      for (int xx = x0; xx <= x1; ++xx) {
        int ax = abs(xx - cx);
        for (int yy = y0; yy <= y1; ++yy) {
          int ay = abs(yy - cy);
          for (int zz = z0; zz <= z1; ++zz) {
            int ch = max(ax, max(ay, abs(zz - cz)));
            if (ch != R) continue;                     // shell only
            int c = (xx << 8) | (yy << 4) | zz;
            for (uint32_t i = starts[c] + sub, e = starts[c + 1]; i < e; i += 4) {
              float4 p4 = pb[i];
              float d2 = dist2_rn(px, py, pz, p4.x, p4.y, p4.z);
              unsigned long long key =
                  ((unsigned long long)__float_as_uint(d2) << 32) |
                  (unsigned long long)__float_as_uint(p4.w);
              bool i0 = key < bk0, i1 = key < bk1, i2 = key < bk2;
              bk2 = i1 ? bk1 : (i2 ? key : bk2);
              bk1 = i0 ? bk0 : (i1 ? key : bk1);
              bk0 = i0 ? key : bk0;
            }
          }
        }
      }
      quad_merge(bk0, bk1, bk2, m0, m1, m2);
      t2f = __uint_as_float((uint32_t)(m2 >> 32));
      float thr = (float)R * H;
      if (t2f < thr * thr * 0.999999f) break;
    }
  }

  if (sub == 0) {
    float d0  = sqrtf(__uint_as_float((uint32_t)(m0 >> 32)));
    float d1  = sqrtf(__uint_as_float((uint32_t)(m1 >> 32)));
    float d2s = sqrtf(__uint_as_float((uint32_t)(m2 >> 32)));
    float r0 = 1.f / (d0 + 1e-8f);
    float r1 = 1.f / (d1 + 1e-8f);
    float r2 = 1.f / (d2s + 1e-8f);
    float inv = 1.f / (r0 + r1 + r2);
    const int jb = b * N_C;
    knn_i[(size_t)dst * 3 + 0] = jb + (int)(m0 & 0xffffffffull);
    knn_i[(size_t)dst * 3 + 1] = jb + (int)(m1 & 0xffffffffull);
    knn_i[(size_t)dst * 3 + 2] = jb + (int)(m2 & 0xffffffffull);
    knn_w[(size_t)dst * 3 + 0] = r0 * inv;
    knn_w[(size_t)dst * 3 + 1] = r1 * inv;
    knn_w[(size_t)dst * 3 + 2] = r2 * inv;
  }
}

// ---------------------------------------------------------------------------
// K3: out = LN(support_feats) @ w1 + b1 + interp(h)   [65536 x 192] x [192 x 192]
// R10: gather phase software-pipelined by hand. R9 showed occupancy is NOT
// the limiter (19.7->25.8% occ, dur flat at 67us): the gather is Little's-law
// bound (~3 outstanding 16B loads/wave at 84 VGPR). This version: knn
// index/weight loads hoisted to kernel top (latency hides under LN+MFMA);
// gather runs as 3 batches of 4 columns with batch k+1's 12 f32x4 loads
// issued before batch k's compute (~24 outstanding loads/wave).
// All arrays fully unrolled, constant indices -> registers (rule #20).
// ---------------------------------------------------------------------------
__global__ __launch_bounds__(256) void k3_ln_gemm_interp(
    const float* __restrict__ sfeats, const float* __restrict__ ln_g,
    const float* __restrict__ ln_b, const __bf16* __restrict__ wt1,
    const float* __restrict__ b1, const float* __restrict__ h,
    const int* __restrict__ knn_i, const float* __restrict__ knn_w,
    float* __restrict__ out)
{
  // single 25.6 KB buffer: A-tile (phases 1-2), then bf16 C-stage (epilogue)
  __shared__ __align__(16) __bf16 sm[64][COUT + 8];
  const int tid = threadIdx.x;
  const int blk = blockIdx.x;
  const int r = tid >> 2, q = tid & 3;
  const int R = blk * 64 + r;

  // ---- Hoisted: 3-NN indices/weights + gather base pointers ----
  const int   gi0 = knn_i[(size_t)R * 3 + 0];
  const int   gi1 = knn_i[(size_t)R * 3 + 1];
  const int   gi2 = knn_i[(size_t)R * 3 + 2];
  const float w0  = knn_w[(size_t)R * 3 + 0];
  const float w1v = knn_w[(size_t)R * 3 + 1];
  const float w2v = knn_w[(size_t)R * 3 + 2];
  const float* h0 = h + (size_t)gi0 * COUT;
  const float* h1 = h + (size_t)gi1 * COUT;
  const float* h2 = h + (size_t)gi2 * COUT;

  // ---- Phase 1: LN (4 threads/row, 12 float4 each) ----
  {
    const float* frow = sfeats + (size_t)R * COUT;
    float4 v[12];
    float sum = 0.f, sumsq = 0.f;
#pragma unroll
    for (int i = 0; i < 12; ++i) {
      float4 t = *(const float4*)(frow + (q + 4 * i) * 4);
      v[i] = t;
      sum   += (t.x + t.y) + (t.z + t.w);
      sumsq += (t.x * t.x + t.y * t.y) + (t.z * t.z + t.w * t.w);
    }
    sum   += __shfl_xor(sum, 1);  sumsq += __shfl_xor(sumsq, 1);
    sum   += __shfl_xor(sum, 2);  sumsq += __shfl_xor(sumsq, 2);
    float mean = sum * (1.f / COUT);
    float var  = sumsq * (1.f / COUT) - mean * mean;
    if (var < 0.f) var = 0.f;
    float rs = rsqrtf(var + LN_EPS);
#pragma unroll
    for (int i = 0; i < 12; ++i) {
      float4 g4 = *(const float4*)(ln_g + (q + 4 * i) * 4);
      float4 b4 = *(const float4*)(ln_b + (q + 4 * i) * 4);
      bf16x4 o;
      o[0] = (__bf16)((v[i].x - mean) * rs * g4.x + b4.x);
      o[1] = (__bf16)((v[i].y - mean) * rs * g4.y + b4.y);
      o[2] = (__bf16)((v[i].z - mean) * rs * g4.z + b4.z);
      o[3] = (__bf16)((v[i].w - mean) * rs * g4.w + b4.w);
      *(bf16x4*)&sm[r][(q + 4 * i) * 4] = o;
    }
  }
  __syncthreads();

  // ---- Phase 2: MFMA ----
  const int w = tid >> 6, lane = tid & 63, m = lane & 15, half = lane >> 4;
  f32x4 acc[12];
#pragma unroll
  for (int t = 0; t < 12; ++t) acc[t] = (f32x4){0.f, 0.f, 0.f, 0.f};

  const __bf16* Arow = &sm[16 * w + m][half * 8];
  const __bf16* Bbase = wt1 + (size_t)m * COUT + half * 8;
#pragma unroll
  for (int ch = 0; ch < 6; ++ch) {
    bf16x8 a = *(const bf16x8*)(Arow + ch * 32);
#pragma unroll
    for (int t = 0; t < 12; ++t) {
      bf16x8 b = *(const bf16x8*)(Bbase + (size_t)(16 * t) * COUT + ch * 32);
      acc[t] = __builtin_amdgcn_mfma_f32_16x16x32_bf16(a, b, acc[t], 0, 0, 0);
    }
  }

  // ---- Stage acc+bias into LDS as bf16 (A-tile no longer needed) ----
  float bv[12];
#pragma unroll
  for (int t = 0; t < 12; ++t) bv[t] = b1[16 * t + m];
  __syncthreads();
  {
    const int rr = 16 * w + half * 4;
#pragma unroll
    for (int t = 0; t < 12; ++t)
#pragma unroll
      for (int reg = 0; reg < 4; ++reg)
        sm[rr + reg][16 * t + m] = (__bf16)(acc[t][reg] + bv[t]);
  }
  __syncthreads();

  // ---- Pipelined gather + store: 3 batches of 4 columns ----
  {
    float* orow = out + (size_t)R * COUT;
    bf16x4 cA[4], cB[4];
    f32x4  a0[4], a1[4], a2[4], b0[4], b1g[4], b2g[4];

    // load batch 0 (cols 0..3 of 12)
#pragma unroll
    for (int j = 0; j < 4; ++j) {
      const int col = 16 * j + 4 * q;
      cA[j] = *(const bf16x4*)&sm[r][col];
      a0[j] = *(const f32x4*)(h0 + col);
      a1[j] = *(const f32x4*)(h1 + col);
      a2[j] = *(const f32x4*)(h2 + col);
    }
    // load batch 1 (cols 4..7)
#pragma unroll
    for (int j = 0; j < 4; ++j) {
      const int col = 16 * (4 + j) + 4 * q;
      cB[j]  = *(const bf16x4*)&sm[r][col];
      b0[j]  = *(const f32x4*)(h0 + col);
      b1g[j] = *(const f32x4*)(h1 + col);
      b2g[j] = *(const f32x4*)(h2 + col);
    }
    // compute+store batch 0
#pragma unroll
    for (int j = 0; j < 4; ++j) {
      const int col = 16 * j + 4 * q;
      f32x4 o;
      o[0] = (float)cA[j][0] + w0 * a0[j][0] + w1v * a1[j][0] + w2v * a2[j][0];
      o[1] = (float)cA[j][1] + w0 * a0[j][1] + w1v * a1[j][1] + w2v * a2[j][1];
      o[2] = (float)cA[j][2] + w0 * a0[j][2] + w1v * a1[j][2] + w2v * a2[j][2];
      o[3] = (float)cA[j][3] + w0 * a0[j][3] + w1v * a1[j][3] + w2v * a2[j][3];
      *(f32x4*)(orow + col) = o;
    }
    // load batch 2 (cols 8..11) into the A slots
#pragma unroll
    for (int j = 0; j < 4; ++j) {
      const int col = 16 * (8 + j) + 4 * q;
      cA[j] = *(const bf16x4*)&sm[r][col];
      a0[j] = *(const f32x4*)(h0 + col);
      a1[j] = *(const f32x4*)(h1 + col);
      a2[j] = *(const f32x4*)(h2 + col);
    }
    // compute+store batch 1
#pragma unroll
    for (int j = 0; j < 4; ++j) {
      const int col = 16 * (4 + j) + 4 * q;
      f32x4 o;
      o[0] = (float)cB[j][0] + w0 * b0[j][0] + w1v * b1g[j][0] + w2v * b2g[j][0];
      o[1] = (float)cB[j][1] + w0 * b0[j][1] + w1v * b1g[j][1] + w2v * b2g[j][1];
      o[2] = (float)cB[j][2] + w0 * b0[j][2] + w1v * b1g[j][2] + w2v * b2g[j][2];
      o[3] = (float)cB[j][3] + w0 * b0[j][3] + w1v * b1g[j][3] + w2v * b2g[j][3];
      *(f32x4*)(orow + col) = o;
    }
    // compute+store batch 2
#pragma unroll
    for (int j = 0; j < 4; ++j) {
      const int col = 16 * (8 + j) + 4 * q;
      f32x4 o;
      o[0] = (float)cA[j][0] + w0 * a0[j][0] + w1v * a1[j][0] + w2v * a2[j][0];
      o[1] = (float)cA[j][1] + w0 * a0[j][1] + w1v * a1[j][1] + w2v * a2[j][1];
      o[2] = (float)cA[j][2] + w0 * a0[j][2] + w1v * a1[j][2] + w2v * a2[j][2];
      o[3] = (float)cA[j][3] + w0 * a0[j][3] + w1v * a1[j][3] + w2v * a2[j][3];
      *(f32x4*)(orow + col) = o;
    }
  }
}

// ---------------------------------------------------------------------------
// K4: passthrough outputs — support_xyz copy + support_offset as float
// ---------------------------------------------------------------------------
__global__ __launch_bounds__(256) void k4_tail(
    const float* __restrict__ sxyz, const int* __restrict__ soff,
    float* __restrict__ out_tail)
{
  const int t = blockIdx.x * 256 + threadIdx.x;
  if (t < MF * 3) out_tail[t] = sxyz[t];
  if (t < B_SEG) out_tail[MF * 3 + t] = (float)soff[t];
}

// ---------------------------------------------------------------------------
extern "C" void kernel_launch(void* const* d_in, const int* in_sizes, int n_in,
                              void* d_out, int out_size, void* d_ws, size_t ws_size,
                              hipStream_t stream)
{
  const float* feats  = (const float*)d_in[0];
  const float* xyz    = (const float*)d_in[1];
  const float* sxyz   = (const float*)d_in[2];
  const float* sfeats = (const float*)d_in[3];
  const int*   soff   = (const int*)d_in[5];
  const float* ln1_g  = (const float*)d_in[6];
  const float* ln1_b  = (const float*)d_in[7];
  const float* w1     = (const float*)d_in[8];
  const float* b1     = (const float*)d_in[9];
  const float* ln2_g  = (const float*)d_in[10];
  const float* ln2_b  = (const float*)d_in[11];
  const float* w2     = (const float*)d_in[12];
  const float* b2     = (const float*)d_in[13];
  float* out = (float*)d_out;

  // workspace layout (float units)
  float*    h       = (float*)d_ws;                        // 16384*192 f32
  int*      knn_i   = (int*)(h + (size_t)MT * COUT);       // 65536*3
  float*    knn_w   = (float*)(knn_i + (size_t)MF * 3);    // 65536*3
  float4*   pts_g   = (float4*)(knn_w + (size_t)MF * 3);   // 4*4096 float4
  uint32_t* starts_g= (uint32_t*)(pts_g + (size_t)B_SEG * N_C);   // 4*4097
  __bf16*   wt2     = (__bf16*)(starts_g + (size_t)B_SEG * (NCELL + 1));
  __bf16*   wt1     = wt2 + (size_t)COUT * CIN;

  k0_prep<<<(CIN * COUT + COUT * COUT) / 256, 256, 0, stream>>>(w2, w1, wt2, wt1);
  kgrid<<<B_SEG, 256, 0, stream>>>(xyz, pts_g, starts_g);
  k1_ln_gemm<<<MT / 64, 256, 0, stream>>>(feats, ln2_g, ln2_b, wt2, b2, h);
  kknn<<<(MF * 4) / 256, 256, 0, stream>>>(sxyz, pts_g, starts_g, knn_i, knn_w);
  k3_ln_gemm_interp<<<MF / 64, 256, 0, stream>>>(sfeats, ln1_g, ln1_b, wt1, b1,
                                                 h, knn_i, knn_w, out);
  k4_tail<<<(MF * 3) / 256, 256, 0, stream>>>(sxyz, soff, out + (size_t)MF * COUT);
}

// Round 11
// 243.471 us; speedup vs baseline: 1.1556x; 1.1419x over previous
//
#include <hip/hip_runtime.h>
#include <cstddef>
#include <cstdint>

// Problem constants (fixed by setup_inputs)
constexpr int B_SEG   = 4;
constexpr int N_C     = 4096;    // coarse points per batch
constexpr int M_F     = 16384;   // fine points per batch
constexpr int CIN     = 384;
constexpr int COUT    = 192;
constexpr int MT      = B_SEG * N_C;   // 16384 coarse rows
constexpr int MF      = B_SEG * M_F;   // 65536 fine rows
constexpr float LN_EPS = 1e-5f;

constexpr int GRES    = 16;            // KNN grid resolution (16^3 cells/batch)
constexpr int NCELL   = GRES * GRES * GRES;   // 4096

typedef __bf16 bf16x8 __attribute__((ext_vector_type(8)));
typedef __bf16 bf16x4 __attribute__((ext_vector_type(4)));
typedef float  f32x4  __attribute__((ext_vector_type(4)));

// ---------------------------------------------------------------------------
// K0: one-time prep — transpose+convert weights to bf16 [n][k] layout.
// ---------------------------------------------------------------------------
__global__ __launch_bounds__(256) void k0_prep(
    const float* __restrict__ w2, const float* __restrict__ w1,
    __bf16* __restrict__ wt2, __bf16* __restrict__ wt1)
{
  int e = blockIdx.x * 256 + threadIdx.x;
  if (e < CIN * COUT) {                       // w2: [384][192] -> wt2 [192][384]
    int k = e / COUT, n = e % COUT;
    wt2[(size_t)n * CIN + k] = (__bf16)w2[e];
  }
  e -= CIN * COUT;
  if (e >= 0 && e < COUT * COUT) {            // w1: [192][192] -> wt1 [192][192]
    int k = e / COUT, n = e % COUT;
    wt1[(size_t)n * COUT + k] = (__bf16)w1[e];
  }
}

// ---------------------------------------------------------------------------
// K1: h = LN(feats) @ w2 + b2      [16384 x 384] x [384 x 192]
// ---------------------------------------------------------------------------
__global__ __launch_bounds__(256) void k1_ln_gemm(
    const float* __restrict__ feats, const float* __restrict__ ln_g,
    const float* __restrict__ ln_b, const __bf16* __restrict__ wt2,
    const float* __restrict__ b2, float* __restrict__ h)
{
  __shared__ __align__(16) __bf16 As[64][CIN + 8];
  const int tid = threadIdx.x;
  const int blk = blockIdx.x;

  // ---- Phase 1: LN (4 threads/row, 24 float4 each) ----
  {
    const int r = tid >> 2, q = tid & 3;
    const float* frow = feats + (size_t)(blk * 64 + r) * CIN;
    float4 v[24];
    float sum = 0.f, sumsq = 0.f;
#pragma unroll
    for (int i = 0; i < 24; ++i) {
      float4 t = *(const float4*)(frow + (q + 4 * i) * 4);
      v[i] = t;
      sum   += (t.x + t.y) + (t.z + t.w);
      sumsq += (t.x * t.x + t.y * t.y) + (t.z * t.z + t.w * t.w);
    }
    sum   += __shfl_xor(sum, 1);  sumsq += __shfl_xor(sumsq, 1);
    sum   += __shfl_xor(sum, 2);  sumsq += __shfl_xor(sumsq, 2);
    float mean = sum * (1.f / CIN);
    float var  = sumsq * (1.f / CIN) - mean * mean;
    if (var < 0.f) var = 0.f;
    float rs = rsqrtf(var + LN_EPS);
#pragma unroll
    for (int i = 0; i < 24; ++i) {
      float4 g4 = *(const float4*)(ln_g + (q + 4 * i) * 4);
      float4 b4 = *(const float4*)(ln_b + (q + 4 * i) * 4);
      bf16x4 o;
      o[0] = (__bf16)((v[i].x - mean) * rs * g4.x + b4.x);
      o[1] = (__bf16)((v[i].y - mean) * rs * g4.y + b4.y);
      o[2] = (__bf16)((v[i].z - mean) * rs * g4.z + b4.z);
      o[3] = (__bf16)((v[i].w - mean) * rs * g4.w + b4.w);
      *(bf16x4*)&As[r][(q + 4 * i) * 4] = o;
    }
  }
  __syncthreads();

  // ---- Phase 2: MFMA ----
  const int w = tid >> 6, lane = tid & 63, m = lane & 15, half = lane >> 4;
  f32x4 acc[12];
#pragma unroll
  for (int t = 0; t < 12; ++t) acc[t] = (f32x4){0.f, 0.f, 0.f, 0.f};

  const __bf16* Arow = &As[16 * w + m][half * 8];
  const __bf16* Bbase = wt2 + (size_t)m * CIN + half * 8;
#pragma unroll
  for (int ch = 0; ch < 12; ++ch) {
    bf16x8 a = *(const bf16x8*)(Arow + ch * 32);
#pragma unroll
    for (int t = 0; t < 12; ++t) {
      bf16x8 b = *(const bf16x8*)(Bbase + (size_t)(16 * t) * CIN + ch * 32);
      acc[t] = __builtin_amdgcn_mfma_f32_16x16x32_bf16(a, b, acc[t], 0, 0, 0);
    }
  }

  // ---- Epilogue: D layout col=lane&15, row=(lane>>4)*4+reg ----
  const int r0 = blk * 64 + 16 * w + half * 4;
#pragma unroll
  for (int t = 0; t < 12; ++t) {
    float bv = b2[16 * t + m];
#pragma unroll
    for (int reg = 0; reg < 4; ++reg)
      h[(size_t)(r0 + reg) * COUT + 16 * t + m] = acc[t][reg] + bv;
  }
}

// ---------------------------------------------------------------------------
// KNN helpers: exact-rounding distance; u64 key (d2_bits<<32)|idx compared
// lexicographically == jax.lax.top_k stable order; order-independent.
// ---------------------------------------------------------------------------
__device__ __forceinline__ float dist2_rn(float px, float py, float pz,
                                          float sx, float sy, float sz)
{
  float dx = __fsub_rn(px, sx);
  float dy = __fsub_rn(py, sy);
  float dz = __fsub_rn(pz, sz);
  return __fadd_rn(__fadd_rn(__fmul_rn(dx, dx), __fmul_rn(dy, dy)),
                   __fmul_rn(dz, dz));
}

// merge two sorted triples -> 3 smallest of the union (branchless 2-pointer).
// PRECONDITION: disjoint candidate sets.
__device__ __forceinline__ void merge3(
    unsigned long long& a0, unsigned long long& a1, unsigned long long& a2,
    unsigned long long b0, unsigned long long b1, unsigned long long b2)
{
  bool t = a0 <= b0;
  unsigned long long r0 = t ? a0 : b0;
  unsigned long long A0 = t ? a1 : a0;
  unsigned long long A1 = t ? a2 : a1;
  unsigned long long B0 = t ? b0 : b1;
  unsigned long long B1 = t ? b1 : b2;
  t = A0 <= B0;
  unsigned long long r1 = t ? A0 : B0;
  unsigned long long C0 = t ? A1 : A0;
  unsigned long long D0 = t ? B0 : B1;
  unsigned long long r2 = C0 <= D0 ? C0 : D0;
  a0 = r0; a1 = r1; a2 = r2;
}

// Quad-wide merged view of 4 PRIVATE per-lane triples -> temporaries only.
__device__ __forceinline__ void quad_merge(
    unsigned long long bk0, unsigned long long bk1, unsigned long long bk2,
    unsigned long long& m0, unsigned long long& m1, unsigned long long& m2)
{
  m0 = bk0; m1 = bk1; m2 = bk2;
  merge3(m0, m1, m2, __shfl_xor(bk0, 1), __shfl_xor(bk1, 1), __shfl_xor(bk2, 1));
  merge3(m0, m1, m2, __shfl_xor(m0, 2), __shfl_xor(m1, 2), __shfl_xor(m2, 2));
}

// scan a contiguous candidate range, sub-strided across the quad
__device__ __forceinline__ void scan_range(
    const float4* __restrict__ pb, uint32_t i0, uint32_t i1, int sub,
    float px, float py, float pz,
    unsigned long long& bk0, unsigned long long& bk1, unsigned long long& bk2)
{
  for (uint32_t i = i0 + sub; i < i1; i += 4) {
    float4 p4 = pb[i];
    float d2 = dist2_rn(px, py, pz, p4.x, p4.y, p4.z);
    unsigned long long key =
        ((unsigned long long)__float_as_uint(d2) << 32) |
        (unsigned long long)__float_as_uint(p4.w);
    bool c0 = key < bk0, c1 = key < bk1, c2 = key < bk2;
    bk2 = c1 ? bk1 : (c2 ? key : bk2);
    bk1 = c0 ? bk0 : (c1 ? key : bk1);
    bk0 = c0 ? key : bk0;
  }
}

// ---------------------------------------------------------------------------
// KG: grid build — one block per batch. LDS histogram over 16^3 cells,
// exclusive scan, counting-sort scatter of float4(x,y,z,id_bits).
// ---------------------------------------------------------------------------
__global__ __launch_bounds__(256) void kgrid(
    const float* __restrict__ xyz,
    float4* __restrict__ pts_g, uint32_t* __restrict__ starts_g)
{
  __shared__ uint32_t cnt[NCELL];
  __shared__ uint32_t bsum[256];
  const int t = threadIdx.x;
  const int b = blockIdx.x;
  const float* src = xyz + (size_t)b * N_C * 3;

#pragma unroll
  for (int i = 0; i < NCELL / 256; ++i) cnt[t + 256 * i] = 0u;
  __syncthreads();

  int   cl[16];
  float xr[16], yr[16], zr[16];
#pragma unroll
  for (int i = 0; i < 16; ++i) {
    int p = i * 256 + t;
    float x = src[3 * p + 0], y = src[3 * p + 1], z = src[3 * p + 2];
    xr[i] = x; yr[i] = y; zr[i] = z;
    int ix = min(GRES - 1, max(0, (int)(x * (float)GRES)));
    int iy = min(GRES - 1, max(0, (int)(y * (float)GRES)));
    int iz = min(GRES - 1, max(0, (int)(z * (float)GRES)));
    int c = (ix << 8) | (iy << 4) | iz;
    cl[i] = c;
    atomicAdd(&cnt[c], 1u);
  }
  __syncthreads();

  uint32_t loc[16], s = 0;
#pragma unroll
  for (int j = 0; j < 16; ++j) { loc[j] = cnt[t * 16 + j]; s += loc[j]; }
  bsum[t] = s;
  __syncthreads();
  for (int off = 1; off < 256; off <<= 1) {
    uint32_t v = (t >= off) ? bsum[t - off] : 0u;
    __syncthreads();
    bsum[t] += v;
    __syncthreads();
  }
  uint32_t run = bsum[t] - s;
#pragma unroll
  for (int j = 0; j < 16; ++j) { cnt[t * 16 + j] = run; run += loc[j]; }
  __syncthreads();

#pragma unroll
  for (int i = 0; i < NCELL / 256; ++i)
    starts_g[(size_t)b * (NCELL + 1) + t + 256 * i] = cnt[t + 256 * i];
  if (t == 0) starts_g[(size_t)b * (NCELL + 1) + NCELL] = N_C;
  __syncthreads();

#pragma unroll
  for (int i = 0; i < 16; ++i) {
    int p = i * 256 + t;
    uint32_t pos = atomicAdd(&cnt[cl[i]], 1u);
    size_t o = (size_t)b * N_C + pos;
    pts_g[o] = make_float4(xr[i], yr[i], zr[i], __uint_as_float((uint32_t)p));
  }
}

// ---------------------------------------------------------------------------
// KNN search: quad-parallel, duplicate-safe merges (R9-verified), and NEW:
// z-merged contiguous ranges. Cells are z-minor in both the cell index and
// the sorted point array, so:
//  - the 3x3x3 box = 9 contiguous ranges (one per (xx,yy))
//  - ring cells with ax==R or ay==R = full z-span (contiguous)
//  - interior ring cells (ax<R && ay<R) = 2 singleton cells (z = cz+-R)
// Identical candidate set; ~3x fewer loop setups, ~2x fewer starts[] reads.
// ---------------------------------------------------------------------------
__global__ __launch_bounds__(256) void kknn(
    const float* __restrict__ sxyz,
    const float4* __restrict__ pts_g, const uint32_t* __restrict__ starts_g,
    int* __restrict__ knn_i, float* __restrict__ knn_w)
{
  __shared__ uint32_t starts[NCELL + 1];
  const int tid = threadIdx.x;
  const int blk = blockIdx.x;            // 1024 blocks, 256 per batch
  const int b   = blk >> 8;

#pragma unroll
  for (int i = 0; i < 17; ++i) {
    int k = tid + 256 * i;
    if (k < NCELL + 1) starts[k] = starts_g[(size_t)b * (NCELL + 1) + k];
  }

  const float4* pb = pts_g + (size_t)b * N_C;
  const int sub = tid & 3;
  const int dst = blk * 64 + (tid >> 2);
  const float px = sxyz[(size_t)dst * 3 + 0];
  const float py = sxyz[(size_t)dst * 3 + 1];
  const float pz = sxyz[(size_t)dst * 3 + 2];
  const int cx = min(GRES - 1, max(0, (int)(px * (float)GRES)));
  const int cy = min(GRES - 1, max(0, (int)(py * (float)GRES)));
  const int cz = min(GRES - 1, max(0, (int)(pz * (float)GRES)));
  __syncthreads();

  unsigned long long bk0 = ~0ull, bk1 = ~0ull, bk2 = ~0ull;   // PRIVATE

  // shells 0..1: 3x3x3 box as 9 contiguous z-ranges
  {
    int xlo = max(cx - 1, 0), xhi = min(cx + 1, GRES - 1);
    int ylo = max(cy - 1, 0), yhi = min(cy + 1, GRES - 1);
    int zlo = max(cz - 1, 0), zhi = min(cz + 1, GRES - 1);
    for (int xx = xlo; xx <= xhi; ++xx)
      for (int yy = ylo; yy <= yhi; ++yy) {
        int base = (xx << 8) | (yy << 4);
        scan_range(pb, starts[base + zlo], starts[base + zhi + 1], sub,
                   px, py, pz, bk0, bk1, bk2);
      }
  }

  unsigned long long m0, m1, m2;
  quad_merge(bk0, bk1, bk2, m0, m1, m2);

  const float H = 1.0f / (float)GRES;
  float t2f = __uint_as_float((uint32_t)(m2 >> 32));    // NaN while <3 found
  if (!(t2f < H * H * 0.999999f)) {
    for (int R = 2; R <= GRES - 1; ++R) {
      int x0 = max(cx - R, 0), x1 = min(cx + R, GRES - 1);
      int y0 = max(cy - R, 0), y1 = min(cy + R, GRES - 1);
      int z0 = max(cz - R, 0), z1 = min(cz + R, GRES - 1);
      for (int xx = x0; xx <= x1; ++xx) {
        int ax = abs(xx - cx);
        for (int yy = y0; yy <= y1; ++yy) {
          int ay = abs(yy - cy);
          int base = (xx << 8) | (yy << 4);
          if (ax == R || ay == R) {
            // full z-span, contiguous
            scan_range(pb, starts[base + z0], starts[base + z1 + 1], sub,
                       px, py, pz, bk0, bk1, bk2);
          } else {
            // only the two z-faces of the shell
            if (cz - R >= 0) {
              int c = base + cz - R;
              scan_range(pb, starts[c], starts[c + 1], sub,
                         px, py, pz, bk0, bk1, bk2);
            }
            if (cz + R <= GRES - 1) {
              int c = base + cz + R;
              scan_range(pb, starts[c], starts[c + 1], sub,
                         px, py, pz, bk0, bk1, bk2);
            }
          }
        }
      }
      quad_merge(bk0, bk1, bk2, m0, m1, m2);
      t2f = __uint_as_float((uint32_t)(m2 >> 32));
      float thr = (float)R * H;
      if (t2f < thr * thr * 0.999999f) break;
    }
  }

  if (sub == 0) {
    float d0  = sqrtf(__uint_as_float((uint32_t)(m0 >> 32)));
    float d1  = sqrtf(__uint_as_float((uint32_t)(m1 >> 32)));
    float d2s = sqrtf(__uint_as_float((uint32_t)(m2 >> 32)));
    float r0 = 1.f / (d0 + 1e-8f);
    float r1 = 1.f / (d1 + 1e-8f);
    float r2 = 1.f / (d2s + 1e-8f);
    float inv = 1.f / (r0 + r1 + r2);
    const int jb = b * N_C;
    knn_i[(size_t)dst * 3 + 0] = jb + (int)(m0 & 0xffffffffull);
    knn_i[(size_t)dst * 3 + 1] = jb + (int)(m1 & 0xffffffffull);
    knn_i[(size_t)dst * 3 + 2] = jb + (int)(m2 & 0xffffffffull);
    knn_w[(size_t)dst * 3 + 0] = r0 * inv;
    knn_w[(size_t)dst * 3 + 1] = r1 * inv;
    knn_w[(size_t)dst * 3 + 2] = r2 * inv;
  }
}

// ---------------------------------------------------------------------------
// K3: out = LN(support_feats) @ w1 + b1 + interp(h)   [65536 x 192] x [192 x 192]
// R11: 512-thread blocks (8 waves). R9/R10 showed the epilogue gather is
// latency-bound and neither occupancy-via-LDS nor source-level ILP moved it;
// the remaining lever is more waves. Each wave now computes a 16-row x 96-col
// half (acc[6], VGPR ~64): same FLOPs, same per-element K order (bit-identical
// output), but 2x waves/block -> up to 32 waves/CU resident.
// LN + gather at 8 threads/row.
// ---------------------------------------------------------------------------
__global__ __launch_bounds__(512) void k3_ln_gemm_interp(
    const float* __restrict__ sfeats, const float* __restrict__ ln_g,
    const float* __restrict__ ln_b, const __bf16* __restrict__ wt1,
    const float* __restrict__ b1, const float* __restrict__ h,
    const int* __restrict__ knn_i, const float* __restrict__ knn_w,
    float* __restrict__ out)
{
  // single 25.6 KB buffer: A-tile (phases 1-2), then bf16 C-stage (epilogue)
  __shared__ __align__(16) __bf16 sm[64][COUT + 8];
  const int tid = threadIdx.x;
  const int blk = blockIdx.x;
  const int r = tid >> 3, q = tid & 7;         // 8 threads per row
  const int R = blk * 64 + r;

  // ---- Hoisted: 3-NN indices/weights (latency hides under LN+MFMA) ----
  const int   gi0 = knn_i[(size_t)R * 3 + 0];
  const int   gi1 = knn_i[(size_t)R * 3 + 1];
  const int   gi2 = knn_i[(size_t)R * 3 + 2];
  const float w0  = knn_w[(size_t)R * 3 + 0];
  const float w1v = knn_w[(size_t)R * 3 + 1];
  const float w2v = knn_w[(size_t)R * 3 + 2];
  const float* h0 = h + (size_t)gi0 * COUT;
  const float* h1 = h + (size_t)gi1 * COUT;
  const float* h2 = h + (size_t)gi2 * COUT;

  // ---- Phase 1: LN (8 threads/row, 6 float4 each) ----
  {
    const float* frow = sfeats + (size_t)R * COUT;
    float4 v[6];
    float sum = 0.f, sumsq = 0.f;
#pragma unroll
    for (int i = 0; i < 6; ++i) {
      float4 t = *(const float4*)(frow + (q + 8 * i) * 4);
      v[i] = t;
      sum   += (t.x + t.y) + (t.z + t.w);
      sumsq += (t.x * t.x + t.y * t.y) + (t.z * t.z + t.w * t.w);
    }
    sum   += __shfl_xor(sum, 1);  sumsq += __shfl_xor(sumsq, 1);
    sum   += __shfl_xor(sum, 2);  sumsq += __shfl_xor(sumsq, 2);
    sum   += __shfl_xor(sum, 4);  sumsq += __shfl_xor(sumsq, 4);
    float mean = sum * (1.f / COUT);
    float var  = sumsq * (1.f / COUT) - mean * mean;
    if (var < 0.f) var = 0.f;
    float rs = rsqrtf(var + LN_EPS);
#pragma unroll
    for (int i = 0; i < 6; ++i) {
      float4 g4 = *(const float4*)(ln_g + (q + 8 * i) * 4);
      float4 b4 = *(const float4*)(ln_b + (q + 8 * i) * 4);
      bf16x4 o;
      o[0] = (__bf16)((v[i].x - mean) * rs * g4.x + b4.x);
      o[1] = (__bf16)((v[i].y - mean) * rs * g4.y + b4.y);
      o[2] = (__bf16)((v[i].z - mean) * rs * g4.z + b4.z);
      o[3] = (__bf16)((v[i].w - mean) * rs * g4.w + b4.w);
      *(bf16x4*)&sm[r][(q + 8 * i) * 4] = o;
    }
  }
  __syncthreads();

  // ---- Phase 2: MFMA — wave w: row-tile w>>1, col-half w&1 ----
  const int w = tid >> 6, lane = tid & 63, m = lane & 15, half = lane >> 4;
  const int wr = w >> 1, nc = w & 1;
  f32x4 acc[6];
#pragma unroll
  for (int t = 0; t < 6; ++t) acc[t] = (f32x4){0.f, 0.f, 0.f, 0.f};

  const __bf16* Arow = &sm[16 * wr + m][half * 8];
  const __bf16* Bbase = wt1 + (size_t)m * COUT + half * 8;
#pragma unroll
  for (int ch = 0; ch < 6; ++ch) {
    bf16x8 a = *(const bf16x8*)(Arow + ch * 32);
#pragma unroll
    for (int t = 0; t < 6; ++t) {
      const int ct = nc * 6 + t;
      bf16x8 b = *(const bf16x8*)(Bbase + (size_t)(16 * ct) * COUT + ch * 32);
      acc[t] = __builtin_amdgcn_mfma_f32_16x16x32_bf16(a, b, acc[t], 0, 0, 0);
    }
  }

  // ---- Stage acc+bias into LDS as bf16 ----
  float bv[6];
#pragma unroll
  for (int t = 0; t < 6; ++t) bv[t] = b1[16 * (nc * 6 + t) + m];
  __syncthreads();
  {
    const int rr = 16 * wr + half * 4;
#pragma unroll
    for (int t = 0; t < 6; ++t) {
      const int col = 16 * (nc * 6 + t) + m;
#pragma unroll
      for (int reg = 0; reg < 4; ++reg)
        sm[rr + reg][col] = (__bf16)(acc[t][reg] + bv[t]);
    }
  }
  __syncthreads();

  // ---- Gather + store: 8 threads/row, 6 float4 columns each ----
  {
    float* orow = out + (size_t)R * COUT;
#pragma unroll
    for (int i = 0; i < 6; ++i) {
      const int col = (q + 8 * i) * 4;
      bf16x4 c4 = *(const bf16x4*)&sm[r][col];
      f32x4 g0 = *(const f32x4*)(h0 + col);
      f32x4 g1 = *(const f32x4*)(h1 + col);
      f32x4 g2 = *(const f32x4*)(h2 + col);
      f32x4 o;
      o[0] = (float)c4[0] + w0 * g0[0] + w1v * g1[0] + w2v * g2[0];
      o[1] = (float)c4[1] + w0 * g0[1] + w1v * g1[1] + w2v * g2[1];
      o[2] = (float)c4[2] + w0 * g0[2] + w1v * g1[2] + w2v * g2[2];
      o[3] = (float)c4[3] + w0 * g0[3] + w1v * g1[3] + w2v * g2[3];
      *(f32x4*)(orow + col) = o;
    }
  }
}

// ---------------------------------------------------------------------------
// K4: passthrough outputs — support_xyz copy + support_offset as float
// ---------------------------------------------------------------------------
__global__ __launch_bounds__(256) void k4_tail(
    const float* __restrict__ sxyz, const int* __restrict__ soff,
    float* __restrict__ out_tail)
{
  const int t = blockIdx.x * 256 + threadIdx.x;
  if (t < MF * 3) out_tail[t] = sxyz[t];
  if (t < B_SEG) out_tail[MF * 3 + t] = (float)soff[t];
}

// ---------------------------------------------------------------------------
extern "C" void kernel_launch(void* const* d_in, const int* in_sizes, int n_in,
                              void* d_out, int out_size, void* d_ws, size_t ws_size,
                              hipStream_t stream)
{
  const float* feats  = (const float*)d_in[0];
  const float* xyz    = (const float*)d_in[1];
  const float* sxyz   = (const float*)d_in[2];
  const float* sfeats = (const float*)d_in[3];
  const int*   soff   = (const int*)d_in[5];
  const float* ln1_g  = (const float*)d_in[6];
  const float* ln1_b  = (const float*)d_in[7];
  const float* w1     = (const float*)d_in[8];
  const float* b1     = (const float*)d_in[9];
  const float* ln2_g  = (const float*)d_in[10];
  const float* ln2_b  = (const float*)d_in[11];
  const float* w2     = (const float*)d_in[12];
  const float* b2     = (const float*)d_in[13];
  float* out = (float*)d_out;

  // workspace layout (float units)
  float*    h       = (float*)d_ws;                        // 16384*192 f32
  int*      knn_i   = (int*)(h + (size_t)MT * COUT);       // 65536*3
  float*    knn_w   = (float*)(knn_i + (size_t)MF * 3);    // 65536*3
  float4*   pts_g   = (float4*)(knn_w + (size_t)MF * 3);   // 4*4096 float4
  uint32_t* starts_g= (uint32_t*)(pts_g + (size_t)B_SEG * N_C);   // 4*4097
  __bf16*   wt2     = (__bf16*)(starts_g + (size_t)B_SEG * (NCELL + 1));
  __bf16*   wt1     = wt2 + (size_t)COUT * CIN;

  k0_prep<<<(CIN * COUT + COUT * COUT) / 256, 256, 0, stream>>>(w2, w1, wt2, wt1);
  kgrid<<<B_SEG, 256, 0, stream>>>(xyz, pts_g, starts_g);
  k1_ln_gemm<<<MT / 64, 256, 0, stream>>>(feats, ln2_g, ln2_b, wt2, b2, h);
  kknn<<<(MF * 4) / 256, 256, 0, stream>>>(sxyz, pts_g, starts_g, knn_i, knn_w);
  k3_ln_gemm_interp<<<MF / 64, 512, 0, stream>>>(sfeats, ln1_g, ln1_b, wt1, b1,
                                                 h, knn_i, knn_w, out);
  k4_tail<<<(MF * 3) / 256, 256, 0, stream>>>(sxyz, soff, out + (size_t)MF * COUT);
}